// Round 2
// baseline (307.190 us; speedup 1.0000x reference)
//
#include <hip/hip_runtime.h>

// Problem constants: B=256, NT=301, D=96, NSEG=50
// linspace(1,301,51) -> segment s = rows [6s, 6s+6] (7 rows).
#define BB 256
#define NT_ 301
#define DD 96
#define NSEG 50
#define SEGROWS 7
#define NTRI (DD * (DD - 1) / 2)   // 4560
#define OUTD (DD + NTRI)           // 4656
// Column-packed LDS: colp[c*CS + t] = seg[t][c]. CS=12 floats (48B):
// 16B-aligned for ds_read_b128, and (12*c)%32 spreads starts over 8 bank-quads
// -> 2-way read aliasing (free). Slots 7..11 are pad.
#define CS 12

// Levy area, algebraically reduced (si[t]*sj[t] cross terms cancel):
//   A_ij = 0.5 * [ sum_{t=1..5} (si[t]*sj[t+1] - si[t+1]*sj[t])
//                  + sj[0]*(si[6]-si[1]) - si[0]*(sj[6]-sj[1]) ]
// The 0.5 is folded into the per-thread row cache.

__global__ __launch_bounds__(256, 4)
void logsig_kernel(const float* __restrict__ inp, float* __restrict__ out) {
    const int bs = blockIdx.x;          // 0 .. B*NSEG-1
    const int b  = bs / NSEG;
    const int s  = bs - b * NSEG;

    __shared__ float colp[DD * CS];     // 4608 B

    // Stage global (row-major, coalesced dwords) -> LDS column-packed.
    const float* __restrict__ src = inp + ((size_t)b * NT_ + (size_t)(6 * s)) * DD;
    for (int idx = threadIdx.x; idx < SEGROWS * DD; idx += 256) {
        const int r = idx / DD;         // magic-mul
        const int c = idx - r * DD;
        colp[c * CS + r] = src[idx];
    }
    __syncthreads();

    const int ty = threadIdx.x >> 4;    // 0..15
    const int tx = threadIdx.x & 15;    // 0..15

    // Row cache: this thread's 6 rows i = 16*ti + ty, pre-scaled by 0.5.
    // rs[ti] = {0.5*s0 .. 0.5*s6, 0.5*(s6-s1)}  (48 VGPRs, static-indexed after unroll)
    float rs[6][8];
    int rowoff[6];
    #pragma unroll
    for (int ti = 0; ti < 6; ++ti) {
        const int i = 16 * ti + ty;
        const float4 lo = *reinterpret_cast<const float4*>(&colp[i * CS]);
        const float4 hi = *reinterpret_cast<const float4*>(&colp[i * CS + 4]);
        rs[ti][0] = 0.5f * lo.x; rs[ti][1] = 0.5f * lo.y;
        rs[ti][2] = 0.5f * lo.z; rs[ti][3] = 0.5f * lo.w;
        rs[ti][4] = 0.5f * hi.x; rs[ti][5] = 0.5f * hi.y;
        rs[ti][6] = 0.5f * hi.z;
        rs[ti][7] = rs[ti][6] - rs[ti][1];                 // 0.5*(s6-s1)
        // triu(k=1) row base: out[DD + i*(2D-1-i)/2 + (j-i-1)] = rowoff[ti] + j
        rowoff[ti] = DD + (i * (2 * DD - 1 - i)) / 2 - i - 1;
    }

    float* __restrict__ o = out + (size_t)bs * OUTD;

    #pragma unroll
    for (int tj = 0; tj < 6; ++tj) {
        const int j = 16 * tj + tx;
        // One column read (2x ds_read_b128) serves up to 6 outputs.
        const float4 lo = *reinterpret_cast<const float4*>(&colp[j * CS]);
        const float4 hi = *reinterpret_cast<const float4*>(&colp[j * CS + 4]);
        const float c0 = lo.x, c1 = lo.y, c2 = lo.z, c3 = lo.w;
        const float c4 = hi.x, c5 = hi.y, c6 = hi.z;       // hi.w is pad
        const float uj = c6 - c1;
        if (ty == 0)
            o[j] = c6 - c0;                                // lvl1 (unscaled)
        #pragma unroll
        for (int ti = 0; ti <= tj; ++ti) {
            // full tiles (ti<tj): always store; diagonal tile: only j>i <=> tx>ty
            if (ti < tj || tx > ty) {
                float acc  = rs[ti][7] * c0 - rs[ti][0] * uj;
                acc += rs[ti][1] * c2 - rs[ti][2] * c1;
                acc += rs[ti][2] * c3 - rs[ti][3] * c2;
                acc += rs[ti][3] * c4 - rs[ti][4] * c3;
                acc += rs[ti][4] * c5 - rs[ti][5] * c4;
                acc += rs[ti][5] * c6 - rs[ti][6] * c5;
                o[rowoff[ti] + j] = acc;
            }
        }
    }
}

extern "C" void kernel_launch(void* const* d_in, const int* in_sizes, int n_in,
                              void* d_out, int out_size, void* d_ws, size_t ws_size,
                              hipStream_t stream) {
    const float* inp = (const float*)d_in[0];
    float* out = (float*)d_out;
    logsig_kernel<<<BB * NSEG, 256, 0, stream>>>(inp, out);
}

// Round 3
// 269.370 us; speedup vs baseline: 1.1404x; 1.1404x over previous
//
#include <hip/hip_runtime.h>

// Problem constants: B=256, NT=301, D=96, NSEG=50
// linspace(1,301,51) -> segment s = rows [6s, 6s+6] (7 rows).
#define BB 256
#define NT_ 301
#define DD 96
#define NSEG 50
#define SEGROWS 7
#define NTRI (DD * (DD - 1) / 2)   // 4560
#define OUTD (DD + NTRI)           // 4656
#define OUTV (OUTD / 4)            // 1164 float4s (OUTD % 4 == 0)
// Column-packed LDS: colp[c*CS + t] = seg[t][c]. CS=12 floats (48B):
// 16B-aligned for ds_read_b128; (12*c)%32 spreads starts over 8 bank-quads.
#define CS 12

// Levy area, algebraically reduced (si[t]*sj[t] cross terms cancel):
//   A_ij = 0.5 * [ sum_{t=1..5} (si[t]*sj[t+1] - si[t+1]*sj[t])
//                  + sj[0]*(si[6]-si[1]) - si[0]*(sj[6]-sj[1]) ]
// 0.5 folded into the per-thread row cache.
//
// v3 change: all outputs staged in LDS obuf, then ONE fully-coalesced
// float4 block copy to global. Theory: scattered 64B wave-stores were the
// bottleneck (238 MB at only 1.74 TB/s effective vs 6.15 TB/s for the
// harness's sequential fill).

__global__ __launch_bounds__(256)
void logsig_kernel(const float* __restrict__ inp, float* __restrict__ out) {
    const int bs = blockIdx.x;          // 0 .. B*NSEG-1
    const int b  = bs / NSEG;
    const int s  = bs - b * NSEG;

    __shared__ float colp[DD * CS];             // 4608 B
    __shared__ __align__(16) float obuf[OUTD];  // 18624 B

    // Stage global (row-major, coalesced dwords) -> LDS column-packed.
    const float* __restrict__ src = inp + ((size_t)b * NT_ + (size_t)(6 * s)) * DD;
    for (int idx = threadIdx.x; idx < SEGROWS * DD; idx += 256) {
        const int r = idx / DD;         // magic-mul
        const int c = idx - r * DD;
        colp[c * CS + r] = src[idx];
    }
    __syncthreads();

    const int ty = threadIdx.x >> 4;    // 0..15
    const int tx = threadIdx.x & 15;    // 0..15

    // Row cache: this thread's 6 rows i = 16*ti + ty, pre-scaled by 0.5.
    float rs[6][8];
    int rowoff[6];
    #pragma unroll
    for (int ti = 0; ti < 6; ++ti) {
        const int i = 16 * ti + ty;
        const float4 lo = *reinterpret_cast<const float4*>(&colp[i * CS]);
        const float4 hi = *reinterpret_cast<const float4*>(&colp[i * CS + 4]);
        rs[ti][0] = 0.5f * lo.x; rs[ti][1] = 0.5f * lo.y;
        rs[ti][2] = 0.5f * lo.z; rs[ti][3] = 0.5f * lo.w;
        rs[ti][4] = 0.5f * hi.x; rs[ti][5] = 0.5f * hi.y;
        rs[ti][6] = 0.5f * hi.z;
        rs[ti][7] = rs[ti][6] - rs[ti][1];                 // 0.5*(s6-s1)
        // triu(k=1) row base: obuf[DD + i*(2D-1-i)/2 + (j-i-1)] = rowoff[ti] + j
        rowoff[ti] = DD + (i * (2 * DD - 1 - i)) / 2 - i - 1;
    }

    #pragma unroll
    for (int tj = 0; tj < 6; ++tj) {
        const int j = 16 * tj + tx;
        // One column read (2x ds_read_b128) serves up to 6 outputs.
        const float4 lo = *reinterpret_cast<const float4*>(&colp[j * CS]);
        const float4 hi = *reinterpret_cast<const float4*>(&colp[j * CS + 4]);
        const float c0 = lo.x, c1 = lo.y, c2 = lo.z, c3 = lo.w;
        const float c4 = hi.x, c5 = hi.y, c6 = hi.z;       // hi.w is pad
        const float uj = c6 - c1;
        if (ty == 0)
            obuf[j] = c6 - c0;                             // lvl1 (unscaled)
        #pragma unroll
        for (int ti = 0; ti <= tj; ++ti) {
            // full tiles (ti<tj): always store; diagonal tile: only j>i <=> tx>ty
            if (ti < tj || tx > ty) {
                float acc  = rs[ti][7] * c0 - rs[ti][0] * uj;
                acc += rs[ti][1] * c2 - rs[ti][2] * c1;
                acc += rs[ti][2] * c3 - rs[ti][3] * c2;
                acc += rs[ti][3] * c4 - rs[ti][4] * c3;
                acc += rs[ti][4] * c5 - rs[ti][5] * c4;
                acc += rs[ti][5] * c6 - rs[ti][6] * c5;
                obuf[rowoff[ti] + j] = acc;                // LDS, ~free conflicts
            }
        }
    }
    __syncthreads();

    // Coalesced epilogue: whole block streams obuf -> out as float4.
    // Per wave: 256B contiguous; blocks cover disjoint contiguous 18.6 KB
    // chunks in near-sorted order -> near-sequential HBM write stream.
    float4* __restrict__ o4 = reinterpret_cast<float4*>(out + (size_t)bs * OUTD);
    const float4* __restrict__ ob4 = reinterpret_cast<const float4*>(obuf);
    #pragma unroll
    for (int k = threadIdx.x; k < OUTV; k += 256)
        o4[k] = ob4[k];
}

extern "C" void kernel_launch(void* const* d_in, const int* in_sizes, int n_in,
                              void* d_out, int out_size, void* d_ws, size_t ws_size,
                              hipStream_t stream) {
    const float* inp = (const float*)d_in[0];
    float* out = (float*)d_out;
    logsig_kernel<<<BB * NSEG, 256, 0, stream>>>(inp, out);
}